// Round 13
// baseline (309.226 us; speedup 1.0000x reference)
//
#include <hip/hip_runtime.h>

typedef unsigned short u16;
typedef unsigned int   u32;
typedef u16  u16x4 __attribute__((ext_vector_type(4)));
typedef u16  u16x8 __attribute__((ext_vector_type(8)));
typedef u32  u32x4 __attribute__((ext_vector_type(4)));
typedef short s16x8 __attribute__((ext_vector_type(8)));
typedef float f32x2 __attribute__((ext_vector_type(2)));
typedef float f32x4 __attribute__((ext_vector_type(4)));

#define DEVFN static __device__ __forceinline__

DEVFN float bf2f(u16 v) { u32 t = (u32)v << 16; return __builtin_bit_cast(float, t); }
DEVFN u16 f2bf(float f) {
  u32 u = __builtin_bit_cast(u32, f);
  return (u16)((u + 0x7fffu + ((u >> 16) & 1u)) >> 16);
}
DEVFN void unpk(u32 w, float& lo, float& hi) {
  lo = __builtin_bit_cast(float, w << 16);
  hi = __builtin_bit_cast(float, w & 0xffff0000u);
}

constexpr int Bb = 8, Tt = 16, Cc = 2048, Hh = 16, HD = 128, ML = 4096;
constexpr int N3 = 3 * Cc;
constexpr float SCALE = 0.08838834764831845f;
constexpr size_t NKV = (size_t)Bb * Hh * ML * HD;   // 67108864
constexpr int NCH = 6;

// ws layout (f32 units) — 4.72 MB guaranteed.
constexpr size_t WS_FLAG = 0;
constexpr size_t WS_QKV  = 16;
constexpr size_t WS_PART = 16;       // 768 slots x 1024 f32 after rot
constexpr size_t WS_QBF  = 786448;
constexpr size_t WS_ATTN = 917520;
constexpr size_t WS_TOTAL = 1179664;

DEVFN int san_cl(int raw) {
  if (raw >= 0 && raw <= ML - Tt) return raw;
  float f = __builtin_bit_cast(float, raw);
  int v = (int)f;
  if (v >= 0 && v <= ML - Tt) return v;
  return 0;
}

// ---------------------------------------------------------------------------
DEVFN int w13_probe1(const u32* p, long long base, long long stride, int lane) {
  u32 w = p[base + (long long)lane * stride];
  u32 e = (w >> 7) & 0xffu;
  unsigned long long b = __ballot(e >= 100u && e <= 140u);
  return (__popcll(b) >= 32) ? 0 : 1;   // 0 = bf16, 1 = f32
}

__global__ void w13_det(const u32* x, const u32* kb, const u32* vb,
                        const u32* wq, const u32* wo, const u32* ct,
                        const u32* st, int* flags)
{
  int lane = threadIdx.x;  // 64
  int f0 = w13_probe1(x,  40000,    997,    lane);
  int f1 = w13_probe1(kb, 10000000, 300001, lane);
  int f2 = w13_probe1(vb, 10000000, 300001, lane);
  int f3 = w13_probe1(wq, 2000000,  33331,  lane);
  int f4 = w13_probe1(wo, 700000,   17177,  lane);
  int f5 = w13_probe1(ct, 40000,    997,    lane);
  int f6 = w13_probe1(st, 40000,    997,    lane);
  if (lane == 0) {
    flags[0] = f0; flags[1] = f1; flags[2] = f2; flags[3] = f3;
    flags[4] = f4; flags[5] = f5; flags[6] = f6; flags[7] = 0;
  }
}

// ---------------------------------------------------------------------------
// MFMA bf16 GEMM core (unchanged from round 12).
// ---------------------------------------------------------------------------
DEVFN void w13_mm_core(const void* __restrict__ A, const void* __restrict__ W,
                       int ldn, int fa, int fw, int kbeg, int m0, int n0,
                       u16 (&As)[64][72], u16 (&Bs)[8][66][8], f32x4 (&acc)[4])
{
  const int tid = threadIdx.x;
  const int l = tid & 63, wv = tid >> 6;
  for (int k0 = kbeg; k0 < kbeg + 512; k0 += 64) {
    __syncthreads();
#pragma unroll
    for (int it = 0; it < 2; ++it) {
      int idx = it * 256 + tid, row = idx >> 3, kc = (idx & 7) * 8;
      if (fa) {
        const float* Af = (const float*)A + (size_t)(m0 + row) * Cc + k0 + kc;
        f32x4 a0 = *(const f32x4*)Af;
        f32x4 a1 = *(const f32x4*)(Af + 4);
        u16x8 av;
#pragma unroll
        for (int u = 0; u < 4; ++u) { av[u] = f2bf(a0[u]); av[u + 4] = f2bf(a1[u]); }
        *(u16x8*)&As[row][kc] = av;
      } else {
        u16x8 av = *(const u16x8*)((const u16*)A + (size_t)(m0 + row) * Cc + k0 + kc);
        *(u16x8*)&As[row][kc] = av;
      }
    }
#pragma unroll
    for (int i = 0; i < 4; ++i) {
      int kk = i * 16 + (tid >> 4);
      int nn = (tid & 15) * 4;
      if (fw) {
        f32x4 bv = *(const f32x4*)((const float*)W + (size_t)(k0 + kk) * ldn + n0 + nn);
#pragma unroll
        for (int u = 0; u < 4; ++u) Bs[kk >> 3][nn + u][kk & 7] = f2bf(bv[u]);
      } else {
        u16x4 bv = *(const u16x4*)((const u16*)W + (size_t)(k0 + kk) * ldn + n0 + nn);
#pragma unroll
        for (int u = 0; u < 4; ++u) Bs[kk >> 3][nn + u][kk & 7] = bv[u];
      }
    }
    __syncthreads();
#pragma unroll
    for (int ks = 0; ks < 2; ++ks) {
      s16x8 a = __builtin_bit_cast(s16x8,
          *(const u16x8*)&As[wv * 16 + (l & 15)][ks * 32 + (l >> 4) * 8]);
#pragma unroll
      for (int nf = 0; nf < 4; ++nf) {
        s16x8 b = __builtin_bit_cast(s16x8,
            *(const u16x8*)&Bs[ks * 4 + (l >> 4)][nf * 16 + (l & 15)][0]);
        acc[nf] = __builtin_amdgcn_mfma_f32_16x16x32_bf16(a, b, acc[nf], 0, 0, 0);
      }
    }
  }
}

__global__ __launch_bounds__(256) void w13_mmp(const void* __restrict__ A,
    const void* __restrict__ W, int ldn, float* __restrict__ part,
    const int* __restrict__ flags)
{
  __shared__ u16 As[64][72];
  __shared__ u16 Bs[8][66][8];
  const int n0 = blockIdx.x * 64, m0 = blockIdx.y * 64, s = blockIdx.z;
  f32x4 acc[4] = {{0.f,0.f,0.f,0.f},{0.f,0.f,0.f,0.f},
                  {0.f,0.f,0.f,0.f},{0.f,0.f,0.f,0.f}};
  w13_mm_core(A, W, ldn, flags[0], flags[3], s * 512, m0, n0, As, Bs, acc);
  const int l = threadIdx.x & 63, wv = threadIdx.x >> 6;
  const int row = m0 + wv * 16 + (l >> 4) * 4;
  const int colb = n0 + (l & 15);
  float* pb = part + (size_t)s * 128 * ldn;
#pragma unroll
  for (int nf = 0; nf < 4; ++nf)
#pragma unroll
    for (int j = 0; j < 4; ++j)
      pb[(size_t)(row + j) * ldn + colb + nf * 16] = acc[nf][j];
}

__global__ __launch_bounds__(256) void w13_red1(const float* __restrict__ part,
                                                float* __restrict__ qkv)
{
  size_t e4 = (size_t)blockIdx.x * 256 + threadIdx.x;
  f32x4 acc = {0.f, 0.f, 0.f, 0.f};
#pragma unroll
  for (int s = 0; s < 4; ++s) {
    f32x4 v = *(const f32x4*)&part[(size_t)s * 786432 + e4 * 4];
    acc[0] += v[0]; acc[1] += v[1]; acc[2] += v[2]; acc[3] += v[3];
  }
  *(f32x4*)&qkv[e4 * 4] = acc;
}

__global__ __launch_bounds__(256) void w13_mma(const float* __restrict__ A,
    const void* __restrict__ W, int ldn, float* __restrict__ outp,
    const int* __restrict__ flags)
{
  __shared__ u16 As[64][72];
  __shared__ u16 Bs[8][66][8];
  const int n0 = blockIdx.x * 64, m0 = blockIdx.y * 64, s = blockIdx.z;
  f32x4 acc[4] = {{0.f,0.f,0.f,0.f},{0.f,0.f,0.f,0.f},
                  {0.f,0.f,0.f,0.f},{0.f,0.f,0.f,0.f}};
  w13_mm_core(A, W, ldn, 1, flags[4], s * 512, m0, n0, As, Bs, acc);
  const int l = threadIdx.x & 63, wv = threadIdx.x >> 6;
  const int row = m0 + wv * 16 + (l >> 4) * 4;
  const int colb = n0 + (l & 15);
#pragma unroll
  for (int nf = 0; nf < 4; ++nf)
#pragma unroll
    for (int j = 0; j < 4; ++j)
      atomicAdd(&outp[(size_t)(row + j) * ldn + colb + nf * 16], acc[nf][j]);
}

__global__ __launch_bounds__(256) void w13_zero(float* __restrict__ outp) {
  size_t i = ((size_t)blockIdx.x * 256 + threadIdx.x) * 4;
  f32x4 z = {0.f, 0.f, 0.f, 0.f};
  *(f32x4*)&outp[i] = z;
}

// ---------------------------------------------------------------------------
__global__ __launch_bounds__(256) void w13_rot(const float* __restrict__ qkv,
    const void* __restrict__ ct, const void* __restrict__ st,
    const int* __restrict__ clp, u16* __restrict__ qbf,
    float* __restrict__ outk, float* __restrict__ outv,
    const int* __restrict__ flags)
{
  const int m = blockIdx.x, b = m >> 4, t = m & 15;
  const int half = blockIdx.y;
  const int cl = san_cl(*clp), pos = cl + t;
  const int fc = flags[5], fs = flags[6];
  const float* qr = qkv + (size_t)m * N3;
  for (int i0 = half * 512 + threadIdx.x; i0 < half * 512 + 512; i0 += 256) {
    int h = i0 >> 6, i = i0 & 63;
    float cs = fc ? ((const float*)ct)[pos * 64 + i] : bf2f(((const u16*)ct)[pos * 64 + i]);
    float sn = fs ? ((const float*)st)[pos * 64 + i] : bf2f(((const u16*)st)[pos * 64 + i]);
    int col = h * HD + 2 * i;
    float q0 = qr[col], q1 = qr[col + 1];
    qbf[(size_t)m * Cc + col]     = f2bf((q0 * cs - q1 * sn) * SCALE);
    qbf[(size_t)m * Cc + col + 1] = f2bf((q1 * cs + q0 * sn) * SCALE);
    float k0 = qr[2048 + col], k1 = qr[2048 + col + 1];
    size_t ko = ((size_t)(b * Hh + h) * ML + pos) * HD + 2 * i;
    outk[ko]     = k0 * cs - k1 * sn;
    outk[ko + 1] = k1 * cs + k0 * sn;
    outv[ko]     = qr[4096 + col];
    outv[ko + 1] = qr[4096 + col + 1];
  }
}

// ---------------------------------------------------------------------------
// attc helpers: register-prefetch load / LDS+copy write of one 64-row tile.
// ---------------------------------------------------------------------------
DEVFN void w13_bkunpk(u32x4 w, f32x4& a, f32x4& b) {
  a[0] = bf2f((u16)(w[0] & 0xffffu)); a[1] = bf2f((u16)(w[0] >> 16));
  a[2] = bf2f((u16)(w[1] & 0xffffu)); a[3] = bf2f((u16)(w[1] >> 16));
  b[0] = bf2f((u16)(w[2] & 0xffffu)); b[1] = bf2f((u16)(w[2] >> 16));
  b[2] = bf2f((u16)(w[3] & 0xffffu)); b[3] = bf2f((u16)(w[3] >> 16));
}

DEVFN void w13_load_tile(const void* kin, const void* vin,
    const float* outk, const float* outv, size_t base, int r0, int rr, int c8,
    int cl, int nl, int fk, int fv,
    f32x4 (&RK)[8], f32x4 (&RV)[8], u32x4 (&BK)[4], u32x4 (&BV)[4])
{
#pragma unroll
  for (int ii = 0; ii < 4; ++ii) {
    int jg = r0 + ii * 16 + rr;
    size_t off = base + (size_t)jg * HD + c8 * 8;
    bool fr = (jg >= cl) && (jg < nl);
    if (fr) {
      RK[2*ii] = *(const f32x4*)&outk[off]; RK[2*ii+1] = *(const f32x4*)&outk[off+4];
      RV[2*ii] = *(const f32x4*)&outv[off]; RV[2*ii+1] = *(const f32x4*)&outv[off+4];
    } else {
      if (fk) {
        RK[2*ii]   = *(const f32x4*)((const float*)kin + off);
        RK[2*ii+1] = *(const f32x4*)((const float*)kin + off + 4);
      } else BK[ii] = *(const u32x4*)((const u16*)kin + off);
      if (fv) {
        RV[2*ii]   = *(const f32x4*)((const float*)vin + off);
        RV[2*ii+1] = *(const f32x4*)((const float*)vin + off + 4);
      } else BV[ii] = *(const u32x4*)((const u16*)vin + off);
    }
  }
}

DEVFN void w13_write_tile(float* outk, float* outv, size_t base, int r0,
    int rr, int c8, int cl, int nl, int fk, int fv,
    const f32x4 (&RK)[8], const f32x4 (&RV)[8],
    const u32x4 (&BK)[4], const u32x4 (&BV)[4],
    u32 (&kls)[64][68], u32 (&vls)[64][68])
{
#pragma unroll
  for (int ii = 0; ii < 4; ++ii) {
    int jg = r0 + ii * 16 + rr;
    int r = ii * 16 + rr;
    size_t off = base + (size_t)jg * HD + c8 * 8;
    bool fr = (jg >= cl) && (jg < nl);
    f32x4 ka, kb, va, vb;
    if (fr || fk) { ka = RK[2*ii]; kb = RK[2*ii+1]; }
    else w13_bkunpk(BK[ii], ka, kb);
    if (fr || fv) { va = RV[2*ii]; vb = RV[2*ii+1]; }
    else w13_bkunpk(BV[ii], va, vb);
    if (!fr) {
      *(f32x4*)&outk[off] = ka; *(f32x4*)&outk[off + 4] = kb;
      *(f32x4*)&outv[off] = va; *(f32x4*)&outv[off + 4] = vb;
    }
    u16x8 kv, vv;
#pragma unroll
    for (int u = 0; u < 4; ++u) {
      kv[u] = f2bf(ka[u]); kv[u + 4] = f2bf(kb[u]);
      vv[u] = f2bf(va[u]); vv[u + 4] = f2bf(vb[u]);
    }
    *(u32x4*)&kls[r][c8 * 4] = __builtin_bit_cast(u32x4, kv);
    *(u32x4*)&vls[r][c8 * 4] = __builtin_bit_cast(u32x4, vv);
  }
}

// ---------------------------------------------------------------------------
// FUSED cache-copy + flash-attention partials, round 13:
//  - phase A (compute tiles): T14 register prefetch of the next tile
//  - phase B (copy-only tiles): pure f32 streaming, no LDS, no barriers
//  - removed the wave-local mid-tile barrier (pls is 16-lane-group-local)
// ---------------------------------------------------------------------------
__global__ __launch_bounds__(256, 3) void w13_attc(
    const void* __restrict__ kin, const void* __restrict__ vin,
    const u16* __restrict__ qbf, const int* __restrict__ clp,
    float* __restrict__ outk, float* __restrict__ outv,
    float* __restrict__ part, float* __restrict__ mlb,
    const int* __restrict__ flags)
{
  __shared__ u32 kls[64][68];
  __shared__ u32 vls[64][68];
  __shared__ u32 qls[16][68];
  __shared__ float pls[16][68];

  const int tid = threadIdx.x;
  const int chunk = blockIdx.x;   // 0..5
  const int bh = blockIdx.y;      // 0..127
  const int cl = san_cl(*clp), nl = cl + Tt;
  const int fk = flags[1], fv = flags[2];
  const size_t base = (size_t)bh * ML * HD;
  const int b = bh >> 4, h = bh & 15;

  { // stage q tile (16 x 128 bf16)
    const u16* qsrc = qbf + (size_t)b * Tt * Cc + h * HD;
    int r = tid >> 4, c8q = tid & 15;
    u16x8 qv = *(const u16x8*)&qsrc[(size_t)r * Cc + c8q * 8];
    *(u32x4*)&qls[r][c8q * 4] = __builtin_bit_cast(u32x4, qv);
  }

  const int t = tid >> 4;
  const int js = tid & 15;
  const int rr = tid >> 4;        // staging row-in-16
  const int c8 = tid & 15;        // staging col-group
  const int qpos = cl + t;
  float m_run = -1e30f, l_run = 0.f;
  float O[8] = {0.f,0.f,0.f,0.f,0.f,0.f,0.f,0.f};

  f32x4 RK[8], RV[8];
  u32x4 BK[4], BV[4];

  int st8 = chunk;
  if (st8 * 64 < nl) {
    w13_load_tile(kin, vin, outk, outv, base, st8 * 64, rr, c8, cl, nl, fk, fv,
                  RK, RV, BK, BV);
    while (true) {
      const int r0 = st8 * 64;
      __syncthreads();
      w13_write_tile(outk, outv, base, r0, rr, c8, cl, nl, fk, fv,
                     RK, RV, BK, BV, kls, vls);
      __syncthreads();
      const int nxt = st8 + NCH;
      const bool more = (nxt * 64 < nl);
      if (more)
        w13_load_tile(kin, vin, outk, outv, base, nxt * 64, rr, c8, cl, nl,
                      fk, fv, RK, RV, BK, BV);

      // ---- S = q_t . k_j for this thread's 4 j's (verified core)
      float s[4] = {0.f,0.f,0.f,0.f};
#pragma unroll
      for (int dblk = 0; dblk < 4; ++dblk) {
        u32x4 qv[4];
#pragma unroll
        for (int g = 0; g < 4; ++g)
          qv[g] = *(const u32x4*)&qls[t][dblk * 16 + g * 4];
        float qf[32];
#pragma unroll
        for (int g = 0; g < 4; ++g)
#pragma unroll
          for (int u = 0; u < 4; ++u)
            unpk(qv[g][u], qf[g * 8 + 2 * u], qf[g * 8 + 2 * u + 1]);
#pragma unroll
        for (int jj = 0; jj < 4; ++jj) {
          const int j = js + jj * 16;
          u32x4 kv4[4];
#pragma unroll
          for (int g = 0; g < 4; ++g)
            kv4[g] = *(const u32x4*)&kls[j][dblk * 16 + g * 4];
          float a_ = s[jj];
#pragma unroll
          for (int g = 0; g < 4; ++g)
#pragma unroll
            for (int u = 0; u < 4; ++u) {
              float lo, hi; unpk(kv4[g][u], lo, hi);
              a_ += qf[g * 8 + 2 * u] * lo;
              a_ += qf[g * 8 + 2 * u + 1] * hi;
            }
          s[jj] = a_;
        }
      }

      // ---- mask + online softmax (16-lane group = one t-row)
      float mt = -1e30f;
      bool val[4];
#pragma unroll
      for (int jj = 0; jj < 4; ++jj) {
        int jg = r0 + js + jj * 16;
        val[jj] = (jg <= qpos);
        if (!val[jj]) s[jj] = -1e30f;
        mt = fmaxf(mt, s[jj]);
      }
#pragma unroll
      for (int w = 1; w < 16; w <<= 1)
        mt = fmaxf(mt, __shfl_xor(mt, w));
      float mn = fmaxf(m_run, mt);
      float crr = __expf(m_run - mn);
      float p[4], ps = 0.f;
#pragma unroll
      for (int jj = 0; jj < 4; ++jj) {
        p[jj] = val[jj] ? __expf(s[jj] - mn) : 0.f;
        ps += p[jj];
      }
#pragma unroll
      for (int w = 1; w < 16; w <<= 1)
        ps += __shfl_xor(ps, w);
      l_run = l_run * crr + ps;
      m_run = mn;
#pragma unroll
      for (int jj = 0; jj < 4; ++jj)
        pls[t][js + jj * 16] = p[jj];
#pragma unroll
      for (int e = 0; e < 8; ++e) O[e] *= crr;
      // (no barrier: pls row t written+read by the same 16-lane group)

      // ---- PV
      const int jmax = (nl - r0 < 64) ? (nl - r0) : 64;
#pragma unroll 2
      for (int j = 0; j < jmax; ++j) {
        float pv = pls[t][j];
        u32x4 vw = *(const u32x4*)&vls[j][js * 4];
#pragma unroll
        for (int g = 0; g < 4; ++g) {
          float lo, hi; unpk(vw[g], lo, hi);
          O[2 * g]     += pv * lo;
          O[2 * g + 1] += pv * hi;
        }
      }

      if (!more) { st8 = nxt; break; }
      st8 = nxt;
    }
  }

  // ---- phase B: copy-only tiles (all rows >= nl, never fresh)
  for (; st8 < 64; st8 += NCH) {
    const int r0 = st8 * 64;
#pragma unroll
    for (int ii = 0; ii < 4; ++ii) {
      int jg = r0 + ii * 16 + rr;
      size_t off = base + (size_t)jg * HD + c8 * 8;
      f32x4 ka, kb, va, vb;
      if (fk) {
        ka = *(const f32x4*)((const float*)kin + off);
        kb = *(const f32x4*)((const float*)kin + off + 4);
      } else w13_bkunpk(*(const u32x4*)((const u16*)kin + off), ka, kb);
      if (fv) {
        va = *(const f32x4*)((const float*)vin + off);
        vb = *(const f32x4*)((const float*)vin + off + 4);
      } else w13_bkunpk(*(const u32x4*)((const u16*)vin + off), va, vb);
      *(f32x4*)&outk[off] = ka; *(f32x4*)&outk[off + 4] = kb;
      *(f32x4*)&outv[off] = va; *(f32x4*)&outv[off + 4] = vb;
    }
  }

  // ---- partial O (bf16) -> ws slot; m,l -> mlb slot
  const int slot = bh * NCH + chunk;
  u16* ob = (u16*)(part + (size_t)slot * 1024);
  u16x8 ov;
#pragma unroll
  for (int e = 0; e < 8; ++e) ov[e] = f2bf(O[e]);
  *(u16x8*)&ob[t * HD + js * 8] = ov;
  if (js == 0) { mlb[slot * 32 + t] = m_run; mlb[slot * 32 + 16 + t] = l_run; }
}

// ---------------------------------------------------------------------------
__global__ __launch_bounds__(128) void w13_comb(const float* __restrict__ part,
    const float* __restrict__ mlb, float* __restrict__ attn)
{
  const int row = blockIdx.x;
  const int d = threadIdx.x;
  const int bh = row >> 4, t = row & 15;
  float M = -1e30f;
#pragma unroll
  for (int c = 0; c < NCH; ++c) M = fmaxf(M, mlb[(bh * NCH + c) * 32 + t]);
  float L = 0.f, acc = 0.f;
#pragma unroll
  for (int c = 0; c < NCH; ++c) {
    const int slot = bh * NCH + c;
    float w = __expf(mlb[slot * 32 + t] - M);
    L   += w * mlb[slot * 32 + 16 + t];
    acc += w * bf2f(((const u16*)(part + (size_t)slot * 1024))[t * HD + d]);
  }
  const int b = bh >> 4, h = bh & 15;
  attn[(size_t)(b * Tt + t) * Cc + h * HD + d] = acc / L;
}

// ---------------------------------------------------------------------------
extern "C" void kernel_launch(void* const* d_in, const int* in_sizes, int n_in,
                              void* d_out, int out_size, void* d_ws, size_t ws_size,
                              hipStream_t stream)
{
  const void* x    = d_in[0];
  const void* kin  = d_in[1];
  const void* vin  = d_in[2];
  const void* wqkv = d_in[3];
  const void* wout = d_in[4];
  const void* ct   = d_in[5];
  const void* st   = d_in[6];
  const int*  clp  = (const int*)d_in[7];

  float* out_f = (float*)d_out;
  float* outk  = out_f + (size_t)Bb * Tt * Cc;
  float* outv  = outk + NKV;
  float* ws = (float*)d_ws;

  if (ws_size < WS_TOTAL * sizeof(float)) return;

  int* flags = (int*)(ws + WS_FLAG);
  u16* qbf   = (u16*)(ws + WS_QBF);

  w13_det<<<1, 64, 0, stream>>>((const u32*)x, (const u32*)kin, (const u32*)vin,
                                (const u32*)wqkv, (const u32*)wout,
                                (const u32*)ct, (const u32*)st, flags);
  w13_mmp<<<dim3(N3 / 64, 2, 4), 256, 0, stream>>>(x, wqkv, N3, outv, flags);
  w13_red1<<<768, 256, 0, stream>>>(outv, ws + WS_QKV);
  w13_rot<<<dim3(128, 2), 256, 0, stream>>>(ws + WS_QKV, ct, st, clp, qbf,
                                            outk, outv, flags);
  w13_attc<<<dim3(NCH, 128), 256, 0, stream>>>(kin, vin, qbf, clp, outk, outv,
                                               ws + WS_PART, out_f, flags);
  w13_comb<<<2048, 128, 0, stream>>>(ws + WS_PART, out_f, ws + WS_ATTN);
  w13_zero<<<256, 256, 0, stream>>>(out_f);
  w13_mma<<<dim3(Cc / 64, 2, 4), 256, 0, stream>>>(ws + WS_ATTN, wout, Cc,
                                                   out_f, flags);
}

// Round 14
// 301.477 us; speedup vs baseline: 1.0257x; 1.0257x over previous
//
#include <hip/hip_runtime.h>

typedef unsigned short u16;
typedef unsigned int   u32;
typedef u16  u16x4 __attribute__((ext_vector_type(4)));
typedef u16  u16x8 __attribute__((ext_vector_type(8)));
typedef u32  u32x4 __attribute__((ext_vector_type(4)));
typedef short s16x8 __attribute__((ext_vector_type(8)));
typedef float f32x2 __attribute__((ext_vector_type(2)));
typedef float f32x4 __attribute__((ext_vector_type(4)));

#define DEVFN static __device__ __forceinline__

DEVFN float bf2f(u16 v) { u32 t = (u32)v << 16; return __builtin_bit_cast(float, t); }
DEVFN u16 f2bf(float f) {
  u32 u = __builtin_bit_cast(u32, f);
  return (u16)((u + 0x7fffu + ((u >> 16) & 1u)) >> 16);
}
DEVFN void unpk(u32 w, float& lo, float& hi) {
  lo = __builtin_bit_cast(float, w << 16);
  hi = __builtin_bit_cast(float, w & 0xffff0000u);
}
DEVFN void bkunpk(u32x4 w, f32x4& a, f32x4& b) {
  a[0] = bf2f((u16)(w[0] & 0xffffu)); a[1] = bf2f((u16)(w[0] >> 16));
  a[2] = bf2f((u16)(w[1] & 0xffffu)); a[3] = bf2f((u16)(w[1] >> 16));
  b[0] = bf2f((u16)(w[2] & 0xffffu)); b[1] = bf2f((u16)(w[2] >> 16));
  b[2] = bf2f((u16)(w[3] & 0xffffu)); b[3] = bf2f((u16)(w[3] >> 16));
}

// non-temporal streaming access (stale K/V copy: zero reuse)
DEVFN f32x4 nt_ld4(const float* p) { return __builtin_nontemporal_load((const f32x4*)p); }
DEVFN u32x4 nt_ld4u(const void* p) { return __builtin_nontemporal_load((const u32x4*)p); }
DEVFN void nt_st4(float* p, f32x4 v) { __builtin_nontemporal_store(v, (f32x4*)p); }

constexpr int Bb = 8, Tt = 16, Cc = 2048, Hh = 16, HD = 128, ML = 4096;
constexpr int N3 = 3 * Cc;
constexpr float SCALE = 0.08838834764831845f;
constexpr size_t NKV = (size_t)Bb * Hh * ML * HD;   // 67108864
constexpr int NCH = 6;

// ws layout (f32 units) — 4.72 MB guaranteed.
constexpr size_t WS_FLAG = 0;
constexpr size_t WS_QKV  = 16;
constexpr size_t WS_PART = 16;       // 768 slots x 1024 f32 after rot
constexpr size_t WS_QBF  = 786448;
constexpr size_t WS_ATTN = 917520;
constexpr size_t WS_TOTAL = 1179664;

DEVFN int san_cl(int raw) {
  if (raw >= 0 && raw <= ML - Tt) return raw;
  float f = __builtin_bit_cast(float, raw);
  int v = (int)f;
  if (v >= 0 && v <= ML - Tt) return v;
  return 0;
}

// ---------------------------------------------------------------------------
DEVFN int w14_probe1(const u32* p, long long base, long long stride, int lane) {
  u32 w = p[base + (long long)lane * stride];
  u32 e = (w >> 7) & 0xffu;
  unsigned long long b = __ballot(e >= 100u && e <= 140u);
  return (__popcll(b) >= 32) ? 0 : 1;   // 0 = bf16, 1 = f32
}

__global__ void w14_det(const u32* x, const u32* kb, const u32* vb,
                        const u32* wq, const u32* wo, const u32* ct,
                        const u32* st, int* flags)
{
  int lane = threadIdx.x;  // 64
  int f0 = w14_probe1(x,  40000,    997,    lane);
  int f1 = w14_probe1(kb, 10000000, 300001, lane);
  int f2 = w14_probe1(vb, 10000000, 300001, lane);
  int f3 = w14_probe1(wq, 2000000,  33331,  lane);
  int f4 = w14_probe1(wo, 700000,   17177,  lane);
  int f5 = w14_probe1(ct, 40000,    997,    lane);
  int f6 = w14_probe1(st, 40000,    997,    lane);
  if (lane == 0) {
    flags[0] = f0; flags[1] = f1; flags[2] = f2; flags[3] = f3;
    flags[4] = f4; flags[5] = f5; flags[6] = f6; flags[7] = 0;
  }
}

// ---------------------------------------------------------------------------
// MFMA bf16 GEMM core (round-12 proven).
// ---------------------------------------------------------------------------
DEVFN void w14_mm_core(const void* __restrict__ A, const void* __restrict__ W,
                       int ldn, int fa, int fw, int kbeg, int m0, int n0,
                       u16 (&As)[64][72], u16 (&Bs)[8][66][8], f32x4 (&acc)[4])
{
  const int tid = threadIdx.x;
  const int l = tid & 63, wv = tid >> 6;
  for (int k0 = kbeg; k0 < kbeg + 512; k0 += 64) {
    __syncthreads();
#pragma unroll
    for (int it = 0; it < 2; ++it) {
      int idx = it * 256 + tid, row = idx >> 3, kc = (idx & 7) * 8;
      if (fa) {
        const float* Af = (const float*)A + (size_t)(m0 + row) * Cc + k0 + kc;
        f32x4 a0 = *(const f32x4*)Af;
        f32x4 a1 = *(const f32x4*)(Af + 4);
        u16x8 av;
#pragma unroll
        for (int u = 0; u < 4; ++u) { av[u] = f2bf(a0[u]); av[u + 4] = f2bf(a1[u]); }
        *(u16x8*)&As[row][kc] = av;
      } else {
        u16x8 av = *(const u16x8*)((const u16*)A + (size_t)(m0 + row) * Cc + k0 + kc);
        *(u16x8*)&As[row][kc] = av;
      }
    }
#pragma unroll
    for (int i = 0; i < 4; ++i) {
      int kk = i * 16 + (tid >> 4);
      int nn = (tid & 15) * 4;
      if (fw) {
        f32x4 bv = *(const f32x4*)((const float*)W + (size_t)(k0 + kk) * ldn + n0 + nn);
#pragma unroll
        for (int u = 0; u < 4; ++u) Bs[kk >> 3][nn + u][kk & 7] = f2bf(bv[u]);
      } else {
        u16x4 bv = *(const u16x4*)((const u16*)W + (size_t)(k0 + kk) * ldn + n0 + nn);
#pragma unroll
        for (int u = 0; u < 4; ++u) Bs[kk >> 3][nn + u][kk & 7] = bv[u];
      }
    }
    __syncthreads();
#pragma unroll
    for (int ks = 0; ks < 2; ++ks) {
      s16x8 a = __builtin_bit_cast(s16x8,
          *(const u16x8*)&As[wv * 16 + (l & 15)][ks * 32 + (l >> 4) * 8]);
#pragma unroll
      for (int nf = 0; nf < 4; ++nf) {
        s16x8 b = __builtin_bit_cast(s16x8,
            *(const u16x8*)&Bs[ks * 4 + (l >> 4)][nf * 16 + (l & 15)][0]);
        acc[nf] = __builtin_amdgcn_mfma_f32_16x16x32_bf16(a, b, acc[nf], 0, 0, 0);
      }
    }
  }
}

__global__ __launch_bounds__(256) void w14_mmp(const void* __restrict__ A,
    const void* __restrict__ W, int ldn, float* __restrict__ part,
    const int* __restrict__ flags)
{
  __shared__ u16 As[64][72];
  __shared__ u16 Bs[8][66][8];
  const int n0 = blockIdx.x * 64, m0 = blockIdx.y * 64, s = blockIdx.z;
  f32x4 acc[4] = {{0.f,0.f,0.f,0.f},{0.f,0.f,0.f,0.f},
                  {0.f,0.f,0.f,0.f},{0.f,0.f,0.f,0.f}};
  w14_mm_core(A, W, ldn, flags[0], flags[3], s * 512, m0, n0, As, Bs, acc);
  const int l = threadIdx.x & 63, wv = threadIdx.x >> 6;
  const int row = m0 + wv * 16 + (l >> 4) * 4;
  const int colb = n0 + (l & 15);
  float* pb = part + (size_t)s * 128 * ldn;
#pragma unroll
  for (int nf = 0; nf < 4; ++nf)
#pragma unroll
    for (int j = 0; j < 4; ++j)
      pb[(size_t)(row + j) * ldn + colb + nf * 16] = acc[nf][j];
}

__global__ __launch_bounds__(256) void w14_red1(const float* __restrict__ part,
                                                float* __restrict__ qkv)
{
  size_t e4 = (size_t)blockIdx.x * 256 + threadIdx.x;
  f32x4 acc = {0.f, 0.f, 0.f, 0.f};
#pragma unroll
  for (int s = 0; s < 4; ++s) {
    f32x4 v = *(const f32x4*)&part[(size_t)s * 786432 + e4 * 4];
    acc[0] += v[0]; acc[1] += v[1]; acc[2] += v[2]; acc[3] += v[3];
  }
  *(f32x4*)&qkv[e4 * 4] = acc;
}

__global__ __launch_bounds__(256) void w14_mma(const float* __restrict__ A,
    const void* __restrict__ W, int ldn, float* __restrict__ outp,
    const int* __restrict__ flags)
{
  __shared__ u16 As[64][72];
  __shared__ u16 Bs[8][66][8];
  const int n0 = blockIdx.x * 64, m0 = blockIdx.y * 64, s = blockIdx.z;
  f32x4 acc[4] = {{0.f,0.f,0.f,0.f},{0.f,0.f,0.f,0.f},
                  {0.f,0.f,0.f,0.f},{0.f,0.f,0.f,0.f}};
  w14_mm_core(A, W, ldn, 1, flags[4], s * 512, m0, n0, As, Bs, acc);
  const int l = threadIdx.x & 63, wv = threadIdx.x >> 6;
  const int row = m0 + wv * 16 + (l >> 4) * 4;
  const int colb = n0 + (l & 15);
#pragma unroll
  for (int nf = 0; nf < 4; ++nf)
#pragma unroll
    for (int j = 0; j < 4; ++j)
      atomicAdd(&outp[(size_t)(row + j) * ldn + colb + nf * 16], acc[nf][j]);
}

__global__ __launch_bounds__(256) void w14_zero(float* __restrict__ outp) {
  size_t i = ((size_t)blockIdx.x * 256 + threadIdx.x) * 4;
  f32x4 z = {0.f, 0.f, 0.f, 0.f};
  *(f32x4*)&outp[i] = z;
}

// ---------------------------------------------------------------------------
__global__ __launch_bounds__(256) void w14_rot(const float* __restrict__ qkv,
    const void* __restrict__ ct, const void* __restrict__ st,
    const int* __restrict__ clp, u16* __restrict__ qbf,
    float* __restrict__ outk, float* __restrict__ outv,
    const int* __restrict__ flags)
{
  const int m = blockIdx.x, b = m >> 4, t = m & 15;
  const int half = blockIdx.y;
  const int cl = san_cl(*clp), pos = cl + t;
  const int fc = flags[5], fs = flags[6];
  const float* qr = qkv + (size_t)m * N3;
  for (int i0 = half * 512 + threadIdx.x; i0 < half * 512 + 512; i0 += 256) {
    int h = i0 >> 6, i = i0 & 63;
    float cs = fc ? ((const float*)ct)[pos * 64 + i] : bf2f(((const u16*)ct)[pos * 64 + i]);
    float sn = fs ? ((const float*)st)[pos * 64 + i] : bf2f(((const u16*)st)[pos * 64 + i]);
    int col = h * HD + 2 * i;
    float q0 = qr[col], q1 = qr[col + 1];
    qbf[(size_t)m * Cc + col]     = f2bf((q0 * cs - q1 * sn) * SCALE);
    qbf[(size_t)m * Cc + col + 1] = f2bf((q1 * cs + q0 * sn) * SCALE);
    float k0 = qr[2048 + col], k1 = qr[2048 + col + 1];
    size_t ko = ((size_t)(b * Hh + h) * ML + pos) * HD + 2 * i;
    outk[ko]     = k0 * cs - k1 * sn;
    outk[ko + 1] = k1 * cs + k0 * sn;
    outv[ko]     = qr[4096 + col];
    outv[ko + 1] = qr[4096 + col + 1];
  }
}

// ---------------------------------------------------------------------------
// FUSED cache-copy + flash-attention partials (round-12 structure, verbatim,
// with NON-TEMPORAL loads/stores on the stale-copy stream — zero reuse data).
// grid (NCH=6, 128 bh), 256 thr.
// ---------------------------------------------------------------------------
__global__ __launch_bounds__(256) void w14_attc(
    const void* __restrict__ kin, const void* __restrict__ vin,
    const u16* __restrict__ qbf, const int* __restrict__ clp,
    float* __restrict__ outk, float* __restrict__ outv,
    float* __restrict__ part, float* __restrict__ mlb,
    const int* __restrict__ flags)
{
  __shared__ u32 kls[64][68];
  __shared__ u32 vls[64][68];
  __shared__ u32 qls[16][68];
  __shared__ float pls[16][68];

  const int tid = threadIdx.x;
  const int chunk = blockIdx.x;   // 0..5
  const int bh = blockIdx.y;      // 0..127
  const int cl = san_cl(*clp), nl = cl + Tt;
  const int fk = flags[1], fv = flags[2];
  const size_t base = (size_t)bh * ML * HD;
  const int b = bh >> 4, h = bh & 15;

  { // stage q tile (16 x 128 bf16)
    const u16* qsrc = qbf + (size_t)b * Tt * Cc + h * HD;
    int r = tid >> 4, c8 = tid & 15;
    u16x8 qv = *(const u16x8*)&qsrc[(size_t)r * Cc + c8 * 8];
    *(u32x4*)&qls[r][c8 * 4] = __builtin_bit_cast(u32x4, qv);
  }

  const int t = tid >> 4;
  const int js = tid & 15;
  const int qpos = cl + t;
  float m_run = -1e30f, l_run = 0.f;
  float O[8] = {0.f,0.f,0.f,0.f,0.f,0.f,0.f,0.f};

  for (int st8 = chunk; st8 < 64; st8 += NCH) {
    const int r0 = st8 * 64;
    __syncthreads();
#pragma unroll
    for (int ii = 0; ii < 4; ++ii) {
      int idx = ii * 256 + tid, r = idx >> 4, c8 = idx & 15;
      int jg = r0 + r;
      size_t off = base + (size_t)jg * HD + c8 * 8;
      bool fresh = (jg >= cl) && (jg < nl);
      f32x4 ka, kb, va, vb;
      if (fresh) {
        ka = *(const f32x4*)&outk[off];
        kb = *(const f32x4*)&outk[off + 4];
        va = *(const f32x4*)&outv[off];
        vb = *(const f32x4*)&outv[off + 4];
      } else {
        if (fk) {
          ka = nt_ld4((const float*)kin + off);
          kb = nt_ld4((const float*)kin + off + 4);
        } else {
          bkunpk(nt_ld4u((const u16*)kin + off), ka, kb);
        }
        if (fv) {
          va = nt_ld4((const float*)vin + off);
          vb = nt_ld4((const float*)vin + off + 4);
        } else {
          bkunpk(nt_ld4u((const u16*)vin + off), va, vb);
        }
        nt_st4(&outk[off], ka);
        nt_st4(&outk[off + 4], kb);
        nt_st4(&outv[off], va);
        nt_st4(&outv[off + 4], vb);
      }
      u16x8 kv, vv;
#pragma unroll
      for (int u = 0; u < 4; ++u) {
        kv[u] = f2bf(ka[u]); kv[u + 4] = f2bf(kb[u]);
        vv[u] = f2bf(va[u]); vv[u + 4] = f2bf(vb[u]);
      }
      *(u32x4*)&kls[r][c8 * 4] = __builtin_bit_cast(u32x4, kv);
      *(u32x4*)&vls[r][c8 * 4] = __builtin_bit_cast(u32x4, vv);
    }
    __syncthreads();
    if (r0 >= nl) continue;

    float s[4] = {0.f,0.f,0.f,0.f};
#pragma unroll
    for (int dblk = 0; dblk < 4; ++dblk) {
      u32x4 qv[4];
#pragma unroll
      for (int g = 0; g < 4; ++g)
        qv[g] = *(const u32x4*)&qls[t][dblk * 16 + g * 4];
      float qf[32];
#pragma unroll
      for (int g = 0; g < 4; ++g)
#pragma unroll
        for (int u = 0; u < 4; ++u)
          unpk(qv[g][u], qf[g * 8 + 2 * u], qf[g * 8 + 2 * u + 1]);
#pragma unroll
      for (int jj = 0; jj < 4; ++jj) {
        const int j = js + jj * 16;
        u32x4 kv4[4];
#pragma unroll
        for (int g = 0; g < 4; ++g)
          kv4[g] = *(const u32x4*)&kls[j][dblk * 16 + g * 4];
        float a_ = s[jj];
#pragma unroll
        for (int g = 0; g < 4; ++g)
#pragma unroll
          for (int u = 0; u < 4; ++u) {
            float lo, hi; unpk(kv4[g][u], lo, hi);
            a_ += qf[g * 8 + 2 * u] * lo;
            a_ += qf[g * 8 + 2 * u + 1] * hi;
          }
        s[jj] = a_;
      }
    }

    float mt = -1e30f;
    bool val[4];
#pragma unroll
    for (int jj = 0; jj < 4; ++jj) {
      int jg = r0 + js + jj * 16;
      val[jj] = (jg <= qpos);
      if (!val[jj]) s[jj] = -1e30f;
      mt = fmaxf(mt, s[jj]);
    }
#pragma unroll
    for (int w = 1; w < 16; w <<= 1)
      mt = fmaxf(mt, __shfl_xor(mt, w));
    float mn = fmaxf(m_run, mt);
    float crr = __expf(m_run - mn);
    float p[4], ps = 0.f;
#pragma unroll
    for (int jj = 0; jj < 4; ++jj) {
      p[jj] = val[jj] ? __expf(s[jj] - mn) : 0.f;
      ps += p[jj];
    }
#pragma unroll
    for (int w = 1; w < 16; w <<= 1)
      ps += __shfl_xor(ps, w);
    l_run = l_run * crr + ps;
    m_run = mn;
#pragma unroll
    for (int jj = 0; jj < 4; ++jj)
      pls[t][js + jj * 16] = p[jj];
#pragma unroll
    for (int e = 0; e < 8; ++e) O[e] *= crr;
    __syncthreads();

    const int jmax = (nl - r0 < 64) ? (nl - r0) : 64;
#pragma unroll 2
    for (int j = 0; j < jmax; ++j) {
      float pv = pls[t][j];
      u32x4 vw = *(const u32x4*)&vls[j][js * 4];
#pragma unroll
      for (int g = 0; g < 4; ++g) {
        float lo, hi; unpk(vw[g], lo, hi);
        O[2 * g]     += pv * lo;
        O[2 * g + 1] += pv * hi;
      }
    }
  }

  // partial O (bf16) -> ws slot; m,l -> mlb slot
  const int slot = bh * NCH + chunk;
  u16* ob = (u16*)(part + (size_t)slot * 1024);
  u16x8 ov;
#pragma unroll
  for (int e = 0; e < 8; ++e) ov[e] = f2bf(O[e]);
  *(u16x8*)&ob[t * HD + js * 8] = ov;
  if (js == 0) { mlb[slot * 32 + t] = m_run; mlb[slot * 32 + 16 + t] = l_run; }
}

// ---------------------------------------------------------------------------
__global__ __launch_bounds__(128) void w14_comb(const float* __restrict__ part,
    const float* __restrict__ mlb, float* __restrict__ attn)
{
  const int row = blockIdx.x;
  const int d = threadIdx.x;
  const int bh = row >> 4, t = row & 15;
  float M = -1e30f;
#pragma unroll
  for (int c = 0; c < NCH; ++c) M = fmaxf(M, mlb[(bh * NCH + c) * 32 + t]);
  float L = 0.f, acc = 0.f;
#pragma unroll
  for (int c = 0; c < NCH; ++c) {
    const int slot = bh * NCH + c;
    float w = __expf(mlb[slot * 32 + t] - M);
    L   += w * mlb[slot * 32 + 16 + t];
    acc += w * bf2f(((const u16*)(part + (size_t)slot * 1024))[t * HD + d]);
  }
  const int b = bh >> 4, h = bh & 15;
  attn[(size_t)(b * Tt + t) * Cc + h * HD + d] = acc / L;
}

// ---------------------------------------------------------------------------
extern "C" void kernel_launch(void* const* d_in, const int* in_sizes, int n_in,
                              void* d_out, int out_size, void* d_ws, size_t ws_size,
                              hipStream_t stream)
{
  const void* x    = d_in[0];
  const void* kin  = d_in[1];
  const void* vin  = d_in[2];
  const void* wqkv = d_in[3];
  const void* wout = d_in[4];
  const void* ct   = d_in[5];
  const void* st   = d_in[6];
  const int*  clp  = (const int*)d_in[7];

  // outputs are f32: (out[262144], k_buf[67108864], v_buf[67108864])
  float* out_f = (float*)d_out;
  float* outk  = out_f + (size_t)Bb * Tt * Cc;
  float* outv  = outk + NKV;
  float* ws = (float*)d_ws;

  if (ws_size < WS_TOTAL * sizeof(float)) return;

  int* flags = (int*)(ws + WS_FLAG);
  u16* qbf   = (u16*)(ws + WS_QBF);

  w14_det<<<1, 64, 0, stream>>>((const u32*)x, (const u32*)kin, (const u32*)vin,
                                (const u32*)wqkv, (const u32*)wout,
                                (const u32*)ct, (const u32*)st, flags);
  // GEMM1 (MFMA, K-split x4): partials parked in dead outv, then reduced
  w14_mmp<<<dim3(N3 / 64, 2, 4), 256, 0, stream>>>(x, wqkv, N3, outv, flags);
  w14_red1<<<768, 256, 0, stream>>>(outv, ws + WS_QKV);
  w14_rot<<<dim3(128, 2), 256, 0, stream>>>(ws + WS_QKV, ct, st, clp, qbf,
                                            outk, outv, flags);
  // fused copy + attention partials (O -> dead qkv region, m/l -> dead out_f)
  w14_attc<<<dim3(NCH, 128), 256, 0, stream>>>(kin, vin, qbf, clp, outk, outv,
                                               ws + WS_PART, out_f, flags);
  w14_comb<<<2048, 128, 0, stream>>>(ws + WS_PART, out_f, ws + WS_ATTN);
  // GEMM2 (MFMA, K-split x4): atomic accumulate into pre-zeroed out
  w14_zero<<<256, 256, 0, stream>>>(out_f);
  w14_mma<<<dim3(Cc / 64, 2, 4), 256, 0, stream>>>(ws + WS_ATTN, wout, Cc,
                                                   out_f, flags);
}